// Round 1
// 274.381 us; speedup vs baseline: 1.1814x; 1.1814x over previous
//
#include <hip/hip_runtime.h>
#include <hip/hip_bf16.h>
#include <cstdint>
#include <cstddef>

// Shapes (fixed): B=4, C=512, H=W=64, N=4096, td=512. Inputs/outputs fp32
// (proven in R4). Compute in bf16 MFMA with fp32 accumulation.
//   x (4,512,4096) | w_qkv (1536,512) | w_dw (1536,25) | w_pw (1536,8) |
//   w_proj (512,1024) | out (4,512,4096) fp32
//
// ws layout (bytes; total ~114.6 MiB):
//   w_qkv_bf  1,572,864 | w_proj_bf 1,048,576 | vk 147,456 |
//   x_t (4,4096,512) bf16 16,777,216 | qkv 50,331,648 | agg 50,331,648
//
// attn is stored head-chunk-transposed over the dead v-rows of qkv/agg:
// chunk(b,h) = 4096 n x 8 d, d contiguous -> proj GEMM B^T staging is
// lane-contiguous for global_load_lds.

typedef __hip_bfloat16 bf16;
typedef __attribute__((ext_vector_type(8))) short short8;
typedef __attribute__((ext_vector_type(4))) float f32x4;

__device__ __forceinline__ float b2f(bf16 v) { return __bfloat162float(v); }
__device__ __forceinline__ bf16 f2b(float v) { return __float2bfloat16(v); }

__device__ __forceinline__ void async16(void* lds_base, const void* gaddr) {
    // dest = lds_base (wave-uniform) + lane*16; per-lane global address.
    __builtin_amdgcn_global_load_lds(
        (const __attribute__((address_space(1))) unsigned int*)gaddr,
        (__attribute__((address_space(3))) unsigned int*)lds_base,
        16, 0, 0);
}

// ---- weight fp32 -> bf16 ----
__global__ __launch_bounds__(256) void convert_kernel(
    const float* __restrict__ src, bf16* __restrict__ dst, int n)
{
    int i = blockIdx.x * 256 + threadIdx.x;
    if (i < n) dst[i] = f2b(src[i]);
}

// ---- x (4,512,4096) fp32 -> x_t (4,4096,512) bf16 ----
__global__ __launch_bounds__(256) void transpose_x_kernel(
    const float* __restrict__ x, bf16* __restrict__ x_t)
{
    __shared__ bf16 tile[32][33];
    const int b = blockIdx.z;
    const int c0 = blockIdx.y * 32;
    const int n0 = blockIdx.x * 32;
    const int tx = threadIdx.x & 31, ty = threadIdx.x >> 5;  // 32x8
    #pragma unroll
    for (int i = 0; i < 32; i += 8)
        tile[ty + i][tx] = f2b(x[((size_t)b * 512 + c0 + ty + i) * 4096 + n0 + tx]);
    __syncthreads();
    #pragma unroll
    for (int i = 0; i < 32; i += 8)
        x_t[((size_t)b * 4096 + n0 + ty + i) * 512 + c0 + tx] = tile[tx][ty + i];
}

// ---- MFMA GEMM, m97 structure: 128x128 tile, BK=32, 4 waves, 64x64/wave ----
// PROJ=false: C[b](1536x4096) bf16 = A(1536x512) * x_t[b]^T ; K=512
// PROJ=true:  out[b](512x4096) f32 = A(512x1024) * attn[b] + x[b] ; K=1024,
//             B^T gathered from head-chunked attn in qkv/agg v-rows.
template <bool PROJ>
__global__ __launch_bounds__(256) void mfma_gemm_kernel(
    const bf16* __restrict__ A, const bf16* __restrict__ xt_or_qkv,
    const bf16* __restrict__ agg, const float* __restrict__ X,
    void* __restrict__ Cout, int M, int K)
{
    constexpr int N = 4096;
    const int b = blockIdx.z;
    const int m_blk = blockIdx.y * 128;
    const int n_blk = blockIdx.x * 128;

    __shared__ short As[128 * 32];   // [row][32k], 64 B rows
    __shared__ short Bs[128 * 32];   // [n][32k] (B^T)

    const int tid = threadIdx.x;
    const int lane = tid & 63, wave = tid >> 6;
    const int wm = (wave >> 1) * 64, wn = (wave & 1) * 64;
    const int fm = lane & 15, fq = lane >> 4;

    f32x4 acc[4][4] = {};

    const short* Ag = (const short*)A;
    const short* Btg = PROJ ? nullptr
        : (const short*)(xt_or_qkv + (size_t)b * N * 512);  // x_t[b], K=512

    for (int k0 = 0; k0 < K; k0 += 32) {
        // stage A: 8 chunks of 16 rows; wave handles chunks {wave, wave+4}
        #pragma unroll
        for (int t0 = 0; t0 < 2; ++t0) {
            int t = wave + t0 * 4;
            int row = m_blk + t * 16 + (lane >> 2);
            int col = k0 + (lane & 3) * 8;
            async16(&As[t * 512], Ag + (size_t)row * K + col);
        }
        // stage B^T
        #pragma unroll
        for (int t0 = 0; t0 < 2; ++t0) {
            int t = wave + t0 * 4;
            int n = n_blk + t * 16 + (lane >> 2);
            if (!PROJ) {
                int col = k0 + (lane & 3) * 8;
                async16(&Bs[t * 512], Btg + (size_t)n * 512 + col);
            } else {
                int h = (k0 >> 3) + (lane & 3);      // 4 heads per k-tile
                const bf16* chunk = (h < 64 ? xt_or_qkv : agg) +
                    ((size_t)b * 1536 + (size_t)(h & 63) * 24 + 16) * 4096;
                async16(&Bs[t * 512], chunk + (size_t)n * 8);
            }
        }
        __syncthreads();   // drains vmcnt before ds_read

        short8 af[4], bfv[4];
        #pragma unroll
        for (int i = 0; i < 4; ++i)
            af[i] = *(const short8*)&As[(wm + i * 16 + fm) * 32 + fq * 8];
        #pragma unroll
        for (int j = 0; j < 4; ++j)
            bfv[j] = *(const short8*)&Bs[(wn + j * 16 + fm) * 32 + fq * 8];
        #pragma unroll
        for (int i = 0; i < 4; ++i)
            #pragma unroll
            for (int j = 0; j < 4; ++j)
                acc[i][j] = __builtin_amdgcn_mfma_f32_16x16x32_bf16(
                    af[i], bfv[j], acc[i][j], 0, 0, 0);
        __syncthreads();
    }

    // epilogue: C/D layout col=lane&15, row=(lane>>4)*4+reg
    if (!PROJ) {
        bf16* Cb = (bf16*)Cout + (size_t)b * M * N;
        #pragma unroll
        for (int i = 0; i < 4; ++i)
            #pragma unroll
            for (int j = 0; j < 4; ++j) {
                int n = n_blk + wn + j * 16 + fm;
                #pragma unroll
                for (int r = 0; r < 4; ++r) {
                    int m = m_blk + wm + i * 16 + fq * 4 + r;
                    Cb[(size_t)m * N + n] = f2b(acc[i][j][r]);
                }
            }
    } else {
        float* Ob = (float*)Cout + (size_t)b * M * N;
        const float* Xb = X + (size_t)b * M * N;
        #pragma unroll
        for (int i = 0; i < 4; ++i)
            #pragma unroll
            for (int j = 0; j < 4; ++j) {
                int n = n_blk + wn + j * 16 + fm;
                #pragma unroll
                for (int r = 0; r < 4; ++r) {
                    int m = m_blk + wm + i * 16 + fq * 4 + r;
                    size_t off = (size_t)m * N + n;
                    Ob[off] = acc[i][j][r] + Xb[off];
                }
            }
    }
}

// ---- fused depthwise 5x5 (pad 2) + grouped pointwise (8->8), v2 ----
// Register-blocked rewrite: tile = full 64-wide x 16-tall per group.
//  * horizontal halo == image padding -> interior staging is aligned
//    128B rows (dwordx4 global loads, no divergence).
//  * LDS fp32 [8][20][68]; stride 68 == 4 (mod 32) -> b128 reads rotate
//    across banks, conflict-free.
//  * each thread computes a 1x4 output strip: per (ch,row) ONE aligned
//    float4 pair (8 floats) feeds 4 outputs via sliding window.
//    LDS reads: 8ch*5row*2 = 80 ds_read_b128 per 4 outputs
//    (vs ~25 conflicting ds_read_b32 per single output before).
__global__ __launch_bounds__(256) void dwpw_kernel(
    const bf16* __restrict__ qkv, const float* __restrict__ w_dw,
    const float* __restrict__ w_pw, bf16* __restrict__ agg)
{
    const int bg = blockIdx.y;           // b*192 + g
    const int b = bg / 192;
    const int g = bg - b * 192;
    const int y0 = blockIdx.x * 16;      // output rows [y0, y0+16)

    __shared__ float s_in[8][20][68];    // col 2..65 = x 0..63; 0,1,66,67 pad
    __shared__ float s_wdw[8][28];       // padded to 28 for float4 reads
    __shared__ float s_wpw[8][8];

    const int tid = threadIdx.x;

    // weights -> LDS
    if (tid < 200) {
        int c = tid / 25, k = tid - c * 25;
        s_wdw[c][k] = w_dw[(size_t)(g * 8 + c) * 25 + k];
    }
    if (tid < 64)
        s_wpw[tid >> 3][tid & 7] = w_pw[(size_t)(g * 8 + (tid >> 3)) * 8 + (tid & 7)];

    // horizontal halo columns (always image padding at full-width tile)
    if (tid < 160) {
        int c = tid / 20, r = tid - c * 20;
        float* row = &s_in[c][r][0];
        row[0] = 0.f; row[1] = 0.f; row[66] = 0.f; row[67] = 0.f;
    }

    const size_t chan_base = ((size_t)b * 1536 + g * 8) * 4096;

    // interior staging: 8ch x 20row x 8 chunks of 8 bf16 = 1280 tasks
    #pragma unroll
    for (int it = 0; it < 5; ++it) {
        int tk = it * 256 + tid;                 // 0..1279
        int c = tk / 160;
        int rem = tk - c * 160;
        int r = rem >> 3;
        int ck = rem & 7;
        int y = y0 + r - 2;
        float f[8];
        if (y >= 0 && y < 64) {
            short8 raw = *(const short8*)(qkv + chan_base + (size_t)c * 4096
                                          + (size_t)y * 64 + ck * 8);
            #pragma unroll
            for (int d = 0; d < 8; ++d)
                f[d] = __uint_as_float(((unsigned)(unsigned short)raw[d]) << 16);
        } else {
            #pragma unroll
            for (int d = 0; d < 8; ++d) f[d] = 0.f;
        }
        float* dst = &s_in[c][r][2 + ck * 8];    // 8B-aligned -> ds_write_b64
        #pragma unroll
        for (int q = 0; q < 4; ++q)
            *(float2*)(dst + 2 * q) = make_float2(f[2 * q], f[2 * q + 1]);
    }
    __syncthreads();

    // compute: thread -> output row py, cols px..px+3
    const int py = tid >> 4;                 // 0..15
    const int px = (tid & 15) * 4;           // 0,4,...,60

    float dwv[8][4];
    #pragma unroll
    for (int c = 0; c < 8; ++c) {
        // hoist 25 dw taps to registers (vectorized LDS broadcast reads)
        float w[25];
        #pragma unroll
        for (int q = 0; q < 6; ++q)
            *(float4*)&w[q * 4] = *(const float4*)&s_wdw[c][q * 4];
        w[24] = s_wdw[c][24];

        float a0 = 0.f, a1 = 0.f, a2 = 0.f, a3 = 0.f;
        #pragma unroll
        for (int i = 0; i < 5; ++i) {
            const float* row = &s_in[c][py + i][px];   // 16B-aligned
            float4 f0 = *(const float4*)row;
            float4 f1 = *(const float4*)(row + 4);
            float f[8] = {f0.x, f0.y, f0.z, f0.w, f1.x, f1.y, f1.z, f1.w};
            #pragma unroll
            for (int j = 0; j < 5; ++j) {
                float wi = w[i * 5 + j];
                a0 += f[j]     * wi;
                a1 += f[j + 1] * wi;
                a2 += f[j + 2] * wi;
                a3 += f[j + 3] * wi;
            }
        }
        dwv[c][0] = a0; dwv[c][1] = a1; dwv[c][2] = a2; dwv[c][3] = a3;
    }

    // grouped pointwise 8->8 + bf16 pack/store (8B per channel, coalesced)
    const size_t out_pix = (size_t)(y0 + py) * 64 + px;
    #pragma unroll
    for (int o = 0; o < 8; ++o) {
        float wv[8];
        *(float4*)&wv[0] = *(const float4*)&s_wpw[o][0];
        *(float4*)&wv[4] = *(const float4*)&s_wpw[o][4];
        float s0 = 0.f, s1 = 0.f, s2 = 0.f, s3 = 0.f;
        #pragma unroll
        for (int i = 0; i < 8; ++i) {
            s0 += dwv[i][0] * wv[i];
            s1 += dwv[i][1] * wv[i];
            s2 += dwv[i][2] * wv[i];
            s3 += dwv[i][3] * wv[i];
        }
        union { bf16 hv[4]; uint2 u; } pk;
        pk.hv[0] = f2b(s0); pk.hv[1] = f2b(s1);
        pk.hv[2] = f2b(s2); pk.hv[3] = f2b(s3);
        *(uint2*)(agg + chan_base + (size_t)o * 4096 + out_pix) = pk.u;
    }
}

// ---- vk[bh,d,e] = sum_n v[d,n]*relu(k[e,n]); row d=8 = sum relu(k) ----
__global__ __launch_bounds__(256) void vk_kernel(
    const bf16* __restrict__ qkv, const bf16* __restrict__ agg,
    float* __restrict__ vk)
{
    const int bh = blockIdx.x;   // 0..511
    const int b = bh >> 7;
    const int h = bh & 127;
    const bf16* base = (h < 64)
        ? (qkv + ((size_t)b * 1536 + h * 24) * 4096)
        : (agg + ((size_t)b * 1536 + (h - 64) * 24) * 4096);

    const int tid = threadIdx.x;
    float acc[9][8] = {};

    for (int n = tid; n < 4096; n += 256) {
        float kv[8], vv[8];
        #pragma unroll
        for (int e = 0; e < 8; ++e) kv[e] = fmaxf(b2f(base[(size_t)(8 + e) * 4096 + n]), 0.f);
        #pragma unroll
        for (int d = 0; d < 8; ++d) vv[d] = b2f(base[(size_t)(16 + d) * 4096 + n]);
        #pragma unroll
        for (int d = 0; d < 8; ++d)
            #pragma unroll
            for (int e = 0; e < 8; ++e)
                acc[d][e] += vv[d] * kv[e];
        #pragma unroll
        for (int e = 0; e < 8; ++e) acc[8][e] += kv[e];
    }

    __shared__ float red[4][72];
    const int lane = tid & 63, wave = tid >> 6;
    #pragma unroll
    for (int d = 0; d < 9; ++d) {
        #pragma unroll
        for (int e = 0; e < 8; ++e) {
            float v = acc[d][e];
            #pragma unroll
            for (int off = 32; off > 0; off >>= 1) v += __shfl_down(v, off, 64);
            if (lane == 0) red[wave][d * 8 + e] = v;
        }
    }
    __syncthreads();
    if (tid < 72) {
        float v = red[0][tid] + red[1][tid] + red[2][tid] + red[3][tid];
        vk[(size_t)bh * 72 + tid] = v;
    }
}

// ---- attn: head-chunk-transposed write over dead v-rows ----
// chunk(b,h)[n][d] at (base + 16*4096) + n*8 + d  (one 16-B store/thread)
__global__ __launch_bounds__(256) void attn_out_kernel(
    bf16* __restrict__ qkv, bf16* __restrict__ agg,
    const float* __restrict__ vk)
{
    const int b = blockIdx.z;
    const int h = blockIdx.y;
    const int n = blockIdx.x * 256 + threadIdx.x;
    bf16* base = (h < 64)
        ? (qkv + ((size_t)b * 1536 + h * 24) * 4096)
        : (agg + ((size_t)b * 1536 + (h - 64) * 24) * 4096);

    __shared__ float s_vk[72];
    if (threadIdx.x < 72)
        s_vk[threadIdx.x] = vk[((size_t)b * 128 + h) * 72 + threadIdx.x];
    __syncthreads();

    float q[8];
    #pragma unroll
    for (int e = 0; e < 8; ++e) q[e] = fmaxf(b2f(base[(size_t)e * 4096 + n]), 0.f);

    float o[9];
    #pragma unroll
    for (int d = 0; d < 9; ++d) {
        float s = 0.f;
        #pragma unroll
        for (int e = 0; e < 8; ++e) s += s_vk[d * 8 + e] * q[e];
        o[d] = s;
    }
    const float denom = o[8] + 1e-15f;

    union { bf16 hv[8]; uint4 u; } pk;
    #pragma unroll
    for (int d = 0; d < 8; ++d) pk.hv[d] = f2b(o[d] / denom);
    *(uint4*)((char*)(base + (size_t)16 * 4096) + (size_t)n * 16) = pk.u;
}

extern "C" void kernel_launch(void* const* d_in, const int* in_sizes, int n_in,
                              void* d_out, int out_size, void* d_ws, size_t ws_size,
                              hipStream_t stream) {
    const float* x      = (const float*)d_in[0];
    const float* w_qkv  = (const float*)d_in[1];
    const float* w_dw   = (const float*)d_in[2];
    const float* w_pw   = (const float*)d_in[3];
    const float* w_proj = (const float*)d_in[4];

    char* ws = (char*)d_ws;
    bf16* w_qkv_bf  = (bf16*)ws;                               // 1,572,864 B
    bf16* w_proj_bf = (bf16*)(ws + 1572864);                   // 1,048,576 B
    float* vkbf     = (float*)(ws + 1572864 + 1048576);        //   147,456 B
    bf16* x_t       = (bf16*)(ws + 1572864 + 1048576 + 147456);          // 16 MiB
    bf16* qkv       = x_t + (size_t)4 * 4096 * 512;            // 48 MiB
    bf16* agg       = qkv + (size_t)4 * 1536 * 4096;           // 48 MiB

    // 0. weight conversion + x transpose
    convert_kernel<<<3072, 256, 0, stream>>>(w_qkv, w_qkv_bf, 786432);
    convert_kernel<<<2048, 256, 0, stream>>>(w_proj, w_proj_bf, 524288);
    transpose_x_kernel<<<dim3(128, 16, 4), 256, 0, stream>>>(x, x_t);

    // 1. qkv = w_qkv (1536x512) @ x[b]  (MFMA, B^T from x_t)
    mfma_gemm_kernel<false><<<dim3(32, 12, 4), 256, 0, stream>>>(
        w_qkv_bf, x_t, nullptr, nullptr, qkv, 1536, 512);

    // 2. agg = grouped-PW(DW5x5(qkv)) — register-blocked v2
    dwpw_kernel<<<dim3(4, 768), 256, 0, stream>>>(qkv, w_dw, w_pw, agg);

    // 3. vk per (b, head)
    vk_kernel<<<dim3(512), 256, 0, stream>>>(qkv, agg, vkbf);

    // 4. attn (normalized), head-chunk-transposed over dead v-rows
    attn_out_kernel<<<dim3(16, 128, 4), 256, 0, stream>>>(qkv, agg, vkbf);

    // 5. out = x + w_proj (512x1024) @ attn[b]  (MFMA, B^T from chunks)
    mfma_gemm_kernel<true><<<dim3(32, 4, 4), 256, 0, stream>>>(
        w_proj_bf, qkv, agg, x, d_out, 512, 1024);
}

// Round 5
// 272.016 us; speedup vs baseline: 1.1917x; 1.0087x over previous
//
#include <hip/hip_runtime.h>
#include <hip/hip_bf16.h>
#include <cstdint>
#include <cstddef>

// Shapes (fixed): B=4, C=512, H=W=64, N=4096, td=512. Inputs/outputs fp32
// (proven in R4). Compute in bf16 MFMA with fp32 accumulation.
//   x (4,512,4096) | w_qkv (1536,512) | w_dw (1536,25) | w_pw (1536,8) |
//   w_proj (512,1024) | out (4,512,4096) fp32
//
// ws layout (bytes; total ~114.6 MiB):
//   w_qkv_bf  1,572,864 | w_proj_bf 1,048,576 | vk 147,456 |
//   x_t (4,4096,512) bf16 16,777,216 | qkv 50,331,648 | agg 50,331,648
//
// attn is stored head-chunk-transposed over the dead v-rows of qkv/agg:
// chunk(b,h) = 4096 n x 8 d, d contiguous -> proj GEMM B^T staging is
// lane-contiguous for global_load_lds.

typedef __hip_bfloat16 bf16;
typedef __attribute__((ext_vector_type(8))) short short8;
typedef __attribute__((ext_vector_type(4))) short short4b;
typedef __attribute__((ext_vector_type(4))) float f32x4;

__device__ __forceinline__ float b2f(bf16 v) { return __bfloat162float(v); }
__device__ __forceinline__ bf16 f2b(float v) { return __float2bfloat16(v); }
__device__ __forceinline__ float us2f(unsigned short u) {
    return __uint_as_float(((unsigned)u) << 16);
}

__device__ __forceinline__ void async16(void* lds_base, const void* gaddr) {
    // dest = lds_base (wave-uniform) + lane*16; per-lane global address.
    __builtin_amdgcn_global_load_lds(
        (const __attribute__((address_space(1))) unsigned int*)gaddr,
        (__attribute__((address_space(3))) unsigned int*)lds_base,
        16, 0, 0);
}

// ---- weight fp32 -> bf16 ----
__global__ __launch_bounds__(256) void convert_kernel(
    const float* __restrict__ src, bf16* __restrict__ dst, int n)
{
    int i = blockIdx.x * 256 + threadIdx.x;
    if (i < n) dst[i] = f2b(src[i]);
}

// ---- x (4,512,4096) fp32 -> x_t (4,4096,512) bf16 ----
__global__ __launch_bounds__(256) void transpose_x_kernel(
    const float* __restrict__ x, bf16* __restrict__ x_t)
{
    __shared__ bf16 tile[32][33];
    const int b = blockIdx.z;
    const int c0 = blockIdx.y * 32;
    const int n0 = blockIdx.x * 32;
    const int tx = threadIdx.x & 31, ty = threadIdx.x >> 5;  // 32x8
    #pragma unroll
    for (int i = 0; i < 32; i += 8)
        tile[ty + i][tx] = f2b(x[((size_t)b * 512 + c0 + ty + i) * 4096 + n0 + tx]);
    __syncthreads();
    #pragma unroll
    for (int i = 0; i < 32; i += 8)
        x_t[((size_t)b * 4096 + n0 + ty + i) * 512 + c0 + tx] = tile[tx][ty + i];
}

// ---- MFMA GEMM, m97 structure: 128x128 tile, BK=32, 4 waves, 64x64/wave ----
// PROJ=false: C[b](1536x4096) bf16 = A(1536x512) * x_t[b]^T ; K=512
// PROJ=true:  out[b](512x4096) f32 = A(512x1024) * attn[b] + x[b] ; K=1024,
//             B^T gathered from head-chunked attn in qkv/agg v-rows.
template <bool PROJ>
__global__ __launch_bounds__(256) void mfma_gemm_kernel(
    const bf16* __restrict__ A, const bf16* __restrict__ xt_or_qkv,
    const bf16* __restrict__ agg, const float* __restrict__ X,
    void* __restrict__ Cout, int M, int K)
{
    constexpr int N = 4096;
    const int b = blockIdx.z;
    const int m_blk = blockIdx.y * 128;
    const int n_blk = blockIdx.x * 128;

    __shared__ short As[128 * 32];   // [row][32k], 64 B rows
    __shared__ short Bs[128 * 32];   // [n][32k] (B^T)

    const int tid = threadIdx.x;
    const int lane = tid & 63, wave = tid >> 6;
    const int wm = (wave >> 1) * 64, wn = (wave & 1) * 64;
    const int fm = lane & 15, fq = lane >> 4;

    f32x4 acc[4][4] = {};

    const short* Ag = (const short*)A;
    const short* Btg = PROJ ? nullptr
        : (const short*)(xt_or_qkv + (size_t)b * N * 512);  // x_t[b], K=512

    for (int k0 = 0; k0 < K; k0 += 32) {
        // stage A: 8 chunks of 16 rows; wave handles chunks {wave, wave+4}
        #pragma unroll
        for (int t0 = 0; t0 < 2; ++t0) {
            int t = wave + t0 * 4;
            int row = m_blk + t * 16 + (lane >> 2);
            int col = k0 + (lane & 3) * 8;
            async16(&As[t * 512], Ag + (size_t)row * K + col);
        }
        // stage B^T
        #pragma unroll
        for (int t0 = 0; t0 < 2; ++t0) {
            int t = wave + t0 * 4;
            int n = n_blk + t * 16 + (lane >> 2);
            if (!PROJ) {
                int col = k0 + (lane & 3) * 8;
                async16(&Bs[t * 512], Btg + (size_t)n * 512 + col);
            } else {
                int h = (k0 >> 3) + (lane & 3);      // 4 heads per k-tile
                const bf16* chunk = (h < 64 ? xt_or_qkv : agg) +
                    ((size_t)b * 1536 + (size_t)(h & 63) * 24 + 16) * 4096;
                async16(&Bs[t * 512], chunk + (size_t)n * 8);
            }
        }
        __syncthreads();   // drains vmcnt before ds_read

        short8 af[4], bfv[4];
        #pragma unroll
        for (int i = 0; i < 4; ++i)
            af[i] = *(const short8*)&As[(wm + i * 16 + fm) * 32 + fq * 8];
        #pragma unroll
        for (int j = 0; j < 4; ++j)
            bfv[j] = *(const short8*)&Bs[(wn + j * 16 + fm) * 32 + fq * 8];
        #pragma unroll
        for (int i = 0; i < 4; ++i)
            #pragma unroll
            for (int j = 0; j < 4; ++j)
                acc[i][j] = __builtin_amdgcn_mfma_f32_16x16x32_bf16(
                    af[i], bfv[j], acc[i][j], 0, 0, 0);
        __syncthreads();
    }

    // epilogue: C/D layout col=lane&15, row=(lane>>4)*4+reg
    if (!PROJ) {
        bf16* Cb = (bf16*)Cout + (size_t)b * M * N;
        #pragma unroll
        for (int i = 0; i < 4; ++i)
            #pragma unroll
            for (int j = 0; j < 4; ++j) {
                int n = n_blk + wn + j * 16 + fm;
                #pragma unroll
                for (int r = 0; r < 4; ++r) {
                    int m = m_blk + wm + i * 16 + fq * 4 + r;
                    Cb[(size_t)m * N + n] = f2b(acc[i][j][r]);
                }
            }
    } else {
        float* Ob = (float*)Cout + (size_t)b * M * N;
        const float* Xb = X + (size_t)b * M * N;
        #pragma unroll
        for (int i = 0; i < 4; ++i)
            #pragma unroll
            for (int j = 0; j < 4; ++j) {
                int n = n_blk + wn + j * 16 + fm;
                #pragma unroll
                for (int r = 0; r < 4; ++r) {
                    int m = m_blk + wm + i * 16 + fq * 4 + r;
                    size_t off = (size_t)m * N + n;
                    Ob[off] = acc[i][j][r] + Xb[off];
                }
            }
    }
}

// ---- fused depthwise 5x5 (pad 2) + grouped pointwise (8->8), v3 ----
// bf16 LDS + 8-col strips: tile 16x64, block = 128 threads (2 waves),
// each thread = 8 cols x 1 row x 8 ch = 64 outputs.
//  * s_in bf16 [8][20][72]: data col x at elem x+2 -> the 12-value window
//    for an 8-col strip is ONE aligned ds_read_b128 + ONE ds_read_b64
//    per (ch,row). Every 8-lane group reads a dense 32-dword run ->
//    conflict-free.
//  * staging: 9 aligned 16B chunks per row; interior chunks are a
//    4B-aligned shifted global read (cols 8ck-2..8ck+5), edge chunks
//    built in registers with zero padding.
__global__ __launch_bounds__(128) void dwpw_kernel(
    const bf16* __restrict__ qkv, const float* __restrict__ w_dw,
    const float* __restrict__ w_pw, bf16* __restrict__ agg)
{
    const int bg = blockIdx.y;           // b*192 + g
    const int b = bg / 192;
    const int g = bg - b * 192;
    const int y0 = blockIdx.x * 16;      // output rows [y0, y0+16)

    __shared__ unsigned short s_in[8][20][72];  // bf16 bits
    __shared__ float s_wdw[8][28];
    __shared__ float s_wpw[8][8];

    const int tid = threadIdx.x;

    for (int i = tid; i < 200; i += 128) {
        int c = i / 25, k = i - c * 25;
        s_wdw[c][k] = w_dw[(size_t)(g * 8 + c) * 25 + k];
    }
    if (tid < 64)
        s_wpw[tid >> 3][tid & 7] = w_pw[(size_t)(g * 8 + (tid >> 3)) * 8 + (tid & 7)];

    const size_t chan_base = ((size_t)b * 1536 + g * 8) * 4096;

    // staging: 8ch x 20row x 9 chunks = 1440 tasks of one 16B LDS write
    for (int it = 0; it < 12; ++it) {
        int idx = it * 128 + tid;
        if (idx >= 1440) break;
        int c = idx / 180;
        int rem = idx - c * 180;
        int r = rem / 9;
        int ck = rem - r * 9;
        int y = y0 + r - 2;
        unsigned short o[8] = {0, 0, 0, 0, 0, 0, 0, 0};
        if (y >= 0 && y < 64) {
            const unsigned short* row =
                (const unsigned short*)(qkv + chan_base + (size_t)c * 4096 + y * 64);
            if (ck == 0) {               // [0,0, cols 0..5]
                unsigned short t[6];
                __builtin_memcpy(t, row, 12);
                #pragma unroll
                for (int q = 0; q < 6; ++q) o[2 + q] = t[q];
            } else if (ck == 8) {        // [cols 62,63, 0 x6]
                __builtin_memcpy(o, row + 62, 4);
            } else {                     // cols 8ck-2 .. 8ck+5 (4B-aligned)
                __builtin_memcpy(o, row + 8 * ck - 2, 16);
            }
        }
        __builtin_memcpy(&s_in[c][r][8 * ck], o, 16);   // 16B-aligned dest
    }
    __syncthreads();

    // compute: thread -> output row py (0..15), cols 8sx..8sx+7
    const int py = tid >> 3;
    const int sx = tid & 7;

    float dwv[8][8];
    #pragma unroll
    for (int c = 0; c < 8; ++c) {
        float w[25];
        #pragma unroll
        for (int q = 0; q < 6; ++q)
            *(float4*)&w[q * 4] = *(const float4*)&s_wdw[c][q * 4];
        w[24] = s_wdw[c][24];

        float a[8] = {};
        #pragma unroll
        for (int i = 0; i < 5; ++i) {
            const unsigned short* rp = &s_in[c][py + i][8 * sx];
            short8 v0 = *(const short8*)rp;            // elems 0..7
            short4b v1 = *(const short4b*)(rp + 8);    // elems 8..11
            float f[12];
            #pragma unroll
            for (int k = 0; k < 8; ++k) f[k] = us2f((unsigned short)v0[k]);
            #pragma unroll
            for (int k = 0; k < 4; ++k) f[8 + k] = us2f((unsigned short)v1[k]);
            #pragma unroll
            for (int j = 0; j < 5; ++j) {
                float wi = w[i * 5 + j];
                #pragma unroll
                for (int x = 0; x < 8; ++x) a[x] += f[j + x] * wi;
            }
        }
        #pragma unroll
        for (int x = 0; x < 8; ++x) dwv[c][x] = a[x];
    }

    // grouped pointwise 8->8 + bf16 pack/store (16B per channel, coalesced)
    const size_t out_pix = (size_t)(y0 + py) * 64 + 8 * sx;
    #pragma unroll
    for (int o = 0; o < 8; ++o) {
        float wv[8];
        *(float4*)&wv[0] = *(const float4*)&s_wpw[o][0];
        *(float4*)&wv[4] = *(const float4*)&s_wpw[o][4];
        float s[8] = {};
        #pragma unroll
        for (int i = 0; i < 8; ++i)
            #pragma unroll
            for (int x = 0; x < 8; ++x) s[x] += dwv[i][x] * wv[i];
        union { bf16 hv[8]; uint4 u; } pk;
        #pragma unroll
        for (int x = 0; x < 8; ++x) pk.hv[x] = f2b(s[x]);
        *(uint4*)(agg + chan_base + (size_t)o * 4096 + out_pix) = pk.u;
    }
}

// ---- vk[bh,d,e] = sum_n v[d,n]*relu(k[e,n]); row d=8 = sum relu(k) ----
__global__ __launch_bounds__(256) void vk_kernel(
    const bf16* __restrict__ qkv, const bf16* __restrict__ agg,
    float* __restrict__ vk)
{
    const int bh = blockIdx.x;   // 0..511
    const int b = bh >> 7;
    const int h = bh & 127;
    const bf16* base = (h < 64)
        ? (qkv + ((size_t)b * 1536 + h * 24) * 4096)
        : (agg + ((size_t)b * 1536 + (h - 64) * 24) * 4096);

    const int tid = threadIdx.x;
    float acc[9][8] = {};

    for (int n = tid; n < 4096; n += 256) {
        float kv[8], vv[8];
        #pragma unroll
        for (int e = 0; e < 8; ++e) kv[e] = fmaxf(b2f(base[(size_t)(8 + e) * 4096 + n]), 0.f);
        #pragma unroll
        for (int d = 0; d < 8; ++d) vv[d] = b2f(base[(size_t)(16 + d) * 4096 + n]);
        #pragma unroll
        for (int d = 0; d < 8; ++d)
            #pragma unroll
            for (int e = 0; e < 8; ++e)
                acc[d][e] += vv[d] * kv[e];
        #pragma unroll
        for (int e = 0; e < 8; ++e) acc[8][e] += kv[e];
    }

    __shared__ float red[4][72];
    const int lane = tid & 63, wave = tid >> 6;
    #pragma unroll
    for (int d = 0; d < 9; ++d) {
        #pragma unroll
        for (int e = 0; e < 8; ++e) {
            float v = acc[d][e];
            #pragma unroll
            for (int off = 32; off > 0; off >>= 1) v += __shfl_down(v, off, 64);
            if (lane == 0) red[wave][d * 8 + e] = v;
        }
    }
    __syncthreads();
    if (tid < 72) {
        float v = red[0][tid] + red[1][tid] + red[2][tid] + red[3][tid];
        vk[(size_t)bh * 72 + tid] = v;
    }
}

// ---- attn: head-chunk-transposed write over dead v-rows ----
// chunk(b,h)[n][d] at (base + 16*4096) + n*8 + d  (one 16-B store/thread)
__global__ __launch_bounds__(256) void attn_out_kernel(
    bf16* __restrict__ qkv, bf16* __restrict__ agg,
    const float* __restrict__ vk)
{
    const int b = blockIdx.z;
    const int h = blockIdx.y;
    const int n = blockIdx.x * 256 + threadIdx.x;
    bf16* base = (h < 64)
        ? (qkv + ((size_t)b * 1536 + h * 24) * 4096)
        : (agg + ((size_t)b * 1536 + (h - 64) * 24) * 4096);

    __shared__ float s_vk[72];
    if (threadIdx.x < 72)
        s_vk[threadIdx.x] = vk[((size_t)b * 128 + h) * 72 + threadIdx.x];
    __syncthreads();

    float q[8];
    #pragma unroll
    for (int e = 0; e < 8; ++e) q[e] = fmaxf(b2f(base[(size_t)e * 4096 + n]), 0.f);

    float o[9];
    #pragma unroll
    for (int d = 0; d < 9; ++d) {
        float s = 0.f;
        #pragma unroll
        for (int e = 0; e < 8; ++e) s += s_vk[d * 8 + e] * q[e];
        o[d] = s;
    }
    const float denom = o[8] + 1e-15f;

    union { bf16 hv[8]; uint4 u; } pk;
    #pragma unroll
    for (int d = 0; d < 8; ++d) pk.hv[d] = f2b(o[d] / denom);
    *(uint4*)((char*)(base + (size_t)16 * 4096) + (size_t)n * 16) = pk.u;
}

extern "C" void kernel_launch(void* const* d_in, const int* in_sizes, int n_in,
                              void* d_out, int out_size, void* d_ws, size_t ws_size,
                              hipStream_t stream) {
    const float* x      = (const float*)d_in[0];
    const float* w_qkv  = (const float*)d_in[1];
    const float* w_dw   = (const float*)d_in[2];
    const float* w_pw   = (const float*)d_in[3];
    const float* w_proj = (const float*)d_in[4];

    char* ws = (char*)d_ws;
    bf16* w_qkv_bf  = (bf16*)ws;                               // 1,572,864 B
    bf16* w_proj_bf = (bf16*)(ws + 1572864);                   // 1,048,576 B
    float* vkbf     = (float*)(ws + 1572864 + 1048576);        //   147,456 B
    bf16* x_t       = (bf16*)(ws + 1572864 + 1048576 + 147456);          // 16 MiB
    bf16* qkv       = x_t + (size_t)4 * 4096 * 512;            // 48 MiB
    bf16* agg       = qkv + (size_t)4 * 1536 * 4096;           // 48 MiB

    // 0. weight conversion + x transpose
    convert_kernel<<<3072, 256, 0, stream>>>(w_qkv, w_qkv_bf, 786432);
    convert_kernel<<<2048, 256, 0, stream>>>(w_proj, w_proj_bf, 524288);
    transpose_x_kernel<<<dim3(128, 16, 4), 256, 0, stream>>>(x, x_t);

    // 1. qkv = w_qkv (1536x512) @ x[b]  (MFMA, B^T from x_t)
    mfma_gemm_kernel<false><<<dim3(32, 12, 4), 256, 0, stream>>>(
        w_qkv_bf, x_t, nullptr, nullptr, qkv, 1536, 512);

    // 2. agg = grouped-PW(DW5x5(qkv)) — bf16-LDS 8-col-strip v3
    dwpw_kernel<<<dim3(4, 768), 128, 0, stream>>>(qkv, w_dw, w_pw, agg);

    // 3. vk per (b, head)
    vk_kernel<<<dim3(512), 256, 0, stream>>>(qkv, agg, vkbf);

    // 4. attn (normalized), head-chunk-transposed over dead v-rows
    attn_out_kernel<<<dim3(16, 128, 4), 256, 0, stream>>>(qkv, agg, vkbf);

    // 5. out = x + w_proj (512x1024) @ attn[b]  (MFMA, B^T from chunks)
    mfma_gemm_kernel<true><<<dim3(32, 4, 4), 256, 0, stream>>>(
        w_proj_bf, qkv, agg, x, d_out, 512, 1024);
}

// Round 7
// 262.091 us; speedup vs baseline: 1.2368x; 1.0379x over previous
//
#include <hip/hip_runtime.h>
#include <hip/hip_bf16.h>
#include <cstdint>
#include <cstddef>

// Shapes (fixed): B=4, C=512, H=W=64, N=4096, td=512. Inputs/outputs fp32
// (proven in R4). Compute in bf16 MFMA with fp32 accumulation.
//   x (4,512,4096) | w_qkv (1536,512) | w_dw (1536,25) | w_pw (1536,8) |
//   w_proj (512,1024) | out (4,512,4096) fp32
//
// ws layout (bytes; total ~114.6 MiB):
//   w_qkv_bf  1,572,864 | w_proj_bf 1,048,576 | vk 147,456 |
//   x_t (4,4096,512) bf16 16,777,216 | qkv 50,331,648 | agg 50,331,648
//
// attn is stored head-chunk-transposed over the dead v-rows of qkv/agg:
// chunk(b,h) = 4096 n x 8 d, d contiguous -> proj GEMM B^T staging is
// lane-contiguous for global_load_lds.

typedef __hip_bfloat16 bf16;
typedef __attribute__((ext_vector_type(8))) short short8;
typedef __attribute__((ext_vector_type(4))) float f32x4;

__device__ __forceinline__ float b2f(bf16 v) { return __bfloat162float(v); }
__device__ __forceinline__ bf16 f2b(float v) { return __float2bfloat16(v); }

__device__ __forceinline__ void async16(void* lds_base, const void* gaddr) {
    // dest = lds_base (wave-uniform) + lane*16; per-lane global address.
    __builtin_amdgcn_global_load_lds(
        (const __attribute__((address_space(1))) unsigned int*)gaddr,
        (__attribute__((address_space(3))) unsigned int*)lds_base,
        16, 0, 0);
}

// ---- weight fp32 -> bf16 ----
__global__ __launch_bounds__(256) void convert_kernel(
    const float* __restrict__ src, bf16* __restrict__ dst, int n)
{
    int i = blockIdx.x * 256 + threadIdx.x;
    if (i < n) dst[i] = f2b(src[i]);
}

// ---- x (4,512,4096) fp32 -> x_t (4,4096,512) bf16 ----
__global__ __launch_bounds__(256) void transpose_x_kernel(
    const float* __restrict__ x, bf16* __restrict__ x_t)
{
    __shared__ bf16 tile[32][33];
    const int b = blockIdx.z;
    const int c0 = blockIdx.y * 32;
    const int n0 = blockIdx.x * 32;
    const int tx = threadIdx.x & 31, ty = threadIdx.x >> 5;  // 32x8
    #pragma unroll
    for (int i = 0; i < 32; i += 8)
        tile[ty + i][tx] = f2b(x[((size_t)b * 512 + c0 + ty + i) * 4096 + n0 + tx]);
    __syncthreads();
    #pragma unroll
    for (int i = 0; i < 32; i += 8)
        x_t[((size_t)b * 4096 + n0 + ty + i) * 512 + c0 + tx] = tile[tx][ty + i];
}

// ---- MFMA GEMM, m97 structure: 128x128 tile, BK=32, 4 waves, 64x64/wave ----
// PROJ=false: C[b](1536x4096) bf16 = A(1536x512) * x_t[b]^T ; K=512
// PROJ=true:  out[b](512x4096) f32 = A(512x1024) * attn[b] + x[b] ; K=1024,
//             B^T gathered from head-chunked attn in qkv/agg v-rows.
template <bool PROJ>
__global__ __launch_bounds__(256) void mfma_gemm_kernel(
    const bf16* __restrict__ A, const bf16* __restrict__ xt_or_qkv,
    const bf16* __restrict__ agg, const float* __restrict__ X,
    void* __restrict__ Cout, int M, int K)
{
    constexpr int N = 4096;
    const int b = blockIdx.z;
    const int m_blk = blockIdx.y * 128;
    const int n_blk = blockIdx.x * 128;

    __shared__ short As[128 * 32];   // [row][32k], 64 B rows
    __shared__ short Bs[128 * 32];   // [n][32k] (B^T)

    const int tid = threadIdx.x;
    const int lane = tid & 63, wave = tid >> 6;
    const int wm = (wave >> 1) * 64, wn = (wave & 1) * 64;
    const int fm = lane & 15, fq = lane >> 4;

    f32x4 acc[4][4] = {};

    const short* Ag = (const short*)A;
    const short* Btg = PROJ ? nullptr
        : (const short*)(xt_or_qkv + (size_t)b * N * 512);  // x_t[b], K=512

    for (int k0 = 0; k0 < K; k0 += 32) {
        // stage A: 8 chunks of 16 rows; wave handles chunks {wave, wave+4}
        #pragma unroll
        for (int t0 = 0; t0 < 2; ++t0) {
            int t = wave + t0 * 4;
            int row = m_blk + t * 16 + (lane >> 2);
            int col = k0 + (lane & 3) * 8;
            async16(&As[t * 512], Ag + (size_t)row * K + col);
        }
        // stage B^T
        #pragma unroll
        for (int t0 = 0; t0 < 2; ++t0) {
            int t = wave + t0 * 4;
            int n = n_blk + t * 16 + (lane >> 2);
            if (!PROJ) {
                int col = k0 + (lane & 3) * 8;
                async16(&Bs[t * 512], Btg + (size_t)n * 512 + col);
            } else {
                int h = (k0 >> 3) + (lane & 3);      // 4 heads per k-tile
                const bf16* chunk = (h < 64 ? xt_or_qkv : agg) +
                    ((size_t)b * 1536 + (size_t)(h & 63) * 24 + 16) * 4096;
                async16(&Bs[t * 512], chunk + (size_t)n * 8);
            }
        }
        __syncthreads();   // drains vmcnt before ds_read

        short8 af[4], bfv[4];
        #pragma unroll
        for (int i = 0; i < 4; ++i)
            af[i] = *(const short8*)&As[(wm + i * 16 + fm) * 32 + fq * 8];
        #pragma unroll
        for (int j = 0; j < 4; ++j)
            bfv[j] = *(const short8*)&Bs[(wn + j * 16 + fm) * 32 + fq * 8];
        #pragma unroll
        for (int i = 0; i < 4; ++i)
            #pragma unroll
            for (int j = 0; j < 4; ++j)
                acc[i][j] = __builtin_amdgcn_mfma_f32_16x16x32_bf16(
                    af[i], bfv[j], acc[i][j], 0, 0, 0);
        __syncthreads();
    }

    // epilogue: C/D layout col=lane&15, row=(lane>>4)*4+reg
    if (!PROJ) {
        bf16* Cb = (bf16*)Cout + (size_t)b * M * N;
        #pragma unroll
        for (int i = 0; i < 4; ++i)
            #pragma unroll
            for (int j = 0; j < 4; ++j) {
                int n = n_blk + wn + j * 16 + fm;
                #pragma unroll
                for (int r = 0; r < 4; ++r) {
                    int m = m_blk + wm + i * 16 + fq * 4 + r;
                    Cb[(size_t)m * N + n] = f2b(acc[i][j][r]);
                }
            }
    } else {
        float* Ob = (float*)Cout + (size_t)b * M * N;
        const float* Xb = X + (size_t)b * M * N;
        #pragma unroll
        for (int i = 0; i < 4; ++i)
            #pragma unroll
            for (int j = 0; j < 4; ++j) {
                int n = n_blk + wn + j * 16 + fm;
                #pragma unroll
                for (int r = 0; r < 4; ++r) {
                    int m = m_blk + wm + i * 16 + fq * 4 + r;
                    size_t off = (size_t)m * N + n;
                    Ob[off] = acc[i][j][r] + Xb[off];
                }
            }
    }
}

// ---- fused depthwise 5x5 (pad 2) + grouped pointwise (8->8), v4 ----
// Direct-from-global: no input LDS, no compute barrier. Tile reuse (5x)
// lives in L1 (wave footprint ~12 rows x 128B = L1-resident). Thread =
// 8-col strip x 1 row x 8 ch. Per (ch,row): ONE aligned dwordx4 (cols
// 8sx..8sx+7) + two dwords (cols 8sx-2,-1 / 8sx+8,+9); row/col validity
// via precomputed masks + v_and -> uniform control flow, no divergence.
// Waves run independently -> occupancy VGPR-bound, latency hidden.
__global__ __launch_bounds__(128) void dwpw_kernel(
    const bf16* __restrict__ qkv, const float* __restrict__ w_dw,
    const float* __restrict__ w_pw, bf16* __restrict__ agg)
{
    const int bg = blockIdx.y;           // b*192 + g
    const int b = bg / 192;
    const int g = bg - b * 192;
    const int y0 = blockIdx.x * 16;      // output rows [y0, y0+16)

    __shared__ float s_wdw[8][28];       // padded for float4 reads
    __shared__ float s_wpw[8][8];

    const int tid = threadIdx.x;

    for (int i = tid; i < 200; i += 128) {
        int c = i / 25, k = i - c * 25;
        s_wdw[c][k] = w_dw[(size_t)(g * 8 + c) * 25 + k];
    }
    if (tid < 64)
        s_wpw[tid >> 3][tid & 7] = w_pw[(size_t)(g * 8 + (tid >> 3)) * 8 + (tid & 7)];
    __syncthreads();

    const int py = tid >> 3;             // 0..15
    const int sx = tid & 7;              // 0..7 (8-col strip)
    const int yq = y0 + py;
    const size_t chan_base = ((size_t)b * 1536 + g * 8) * 4096;

    // per-thread column-edge setup (branchless thereafter)
    const int lo_off = (sx > 0) ? 16 * sx - 4 : 0;    // bytes: cols 8sx-2,-1
    const int hi_off = (sx < 7) ? 16 * sx + 16 : 0;   // bytes: cols 8sx+8,+9
    const unsigned lo_keep = (sx > 0) ? 0xFFFFFFFFu : 0u;
    const unsigned hi_keep = (sx < 7) ? 0xFFFFFFFFu : 0u;

    float dwv[8][8];
    #pragma unroll
    for (int c = 0; c < 8; ++c) {
        float w[25];
        #pragma unroll
        for (int q = 0; q < 6; ++q)
            *(float4*)&w[q * 4] = *(const float4*)&s_wdw[c][q * 4];
        w[24] = s_wdw[c][24];

        const char* cbase = (const char*)(qkv + chan_base + (size_t)c * 4096);
        float a[8] = {};
        #pragma unroll
        for (int i = 0; i < 5; ++i) {
            const int y = yq + i - 2;
            const bool row_ok = ((unsigned)y < 64u);
            const int yc = row_ok ? y : 0;             // safe address
            const char* rowp = cbase + yc * 128;       // 128 B per row
            uint4 mid = *(const uint4*)(rowp + 16 * sx);
            unsigned lo = *(const unsigned*)(rowp + lo_off);
            unsigned hi = *(const unsigned*)(rowp + hi_off);
            const unsigned m = row_ok ? 0xFFFFFFFFu : 0u;
            lo &= m & lo_keep;
            hi &= m & hi_keep;
            mid.x &= m; mid.y &= m; mid.z &= m; mid.w &= m;

            float f[12];
            f[0]  = __uint_as_float(lo << 16);
            f[1]  = __uint_as_float(lo & 0xFFFF0000u);
            f[2]  = __uint_as_float(mid.x << 16);
            f[3]  = __uint_as_float(mid.x & 0xFFFF0000u);
            f[4]  = __uint_as_float(mid.y << 16);
            f[5]  = __uint_as_float(mid.y & 0xFFFF0000u);
            f[6]  = __uint_as_float(mid.z << 16);
            f[7]  = __uint_as_float(mid.z & 0xFFFF0000u);
            f[8]  = __uint_as_float(mid.w << 16);
            f[9]  = __uint_as_float(mid.w & 0xFFFF0000u);
            f[10] = __uint_as_float(hi << 16);
            f[11] = __uint_as_float(hi & 0xFFFF0000u);

            #pragma unroll
            for (int j = 0; j < 5; ++j) {
                float wi = w[i * 5 + j];
                #pragma unroll
                for (int x = 0; x < 8; ++x) a[x] += f[j + x] * wi;
            }
        }
        #pragma unroll
        for (int x = 0; x < 8; ++x) dwv[c][x] = a[x];
    }

    // grouped pointwise 8->8 + bf16 pack/store (16B per channel, coalesced)
    const size_t out_pix = (size_t)yq * 64 + 8 * sx;
    #pragma unroll
    for (int o = 0; o < 8; ++o) {
        float wv[8];
        *(float4*)&wv[0] = *(const float4*)&s_wpw[o][0];
        *(float4*)&wv[4] = *(const float4*)&s_wpw[o][4];
        float s[8] = {};
        #pragma unroll
        for (int i = 0; i < 8; ++i)
            #pragma unroll
            for (int x = 0; x < 8; ++x) s[x] += dwv[i][x] * wv[i];
        union { bf16 hv[8]; uint4 u; } pk;
        #pragma unroll
        for (int x = 0; x < 8; ++x) pk.hv[x] = f2b(s[x]);
        *(uint4*)(agg + chan_base + (size_t)o * 4096 + out_pix) = pk.u;
    }
}

// ---- vk[bh,d,e] = sum_n v[d,n]*relu(k[e,n]); row d=8 = sum relu(k) ----
__global__ __launch_bounds__(256) void vk_kernel(
    const bf16* __restrict__ qkv, const bf16* __restrict__ agg,
    float* __restrict__ vk)
{
    const int bh = blockIdx.x;   // 0..511
    const int b = bh >> 7;
    const int h = bh & 127;
    const bf16* base = (h < 64)
        ? (qkv + ((size_t)b * 1536 + h * 24) * 4096)
        : (agg + ((size_t)b * 1536 + (h - 64) * 24) * 4096);

    const int tid = threadIdx.x;
    float acc[9][8] = {};

    for (int n = tid; n < 4096; n += 256) {
        float kv[8], vv[8];
        #pragma unroll
        for (int e = 0; e < 8; ++e) kv[e] = fmaxf(b2f(base[(size_t)(8 + e) * 4096 + n]), 0.f);
        #pragma unroll
        for (int d = 0; d < 8; ++d) vv[d] = b2f(base[(size_t)(16 + d) * 4096 + n]);
        #pragma unroll
        for (int d = 0; d < 8; ++d)
            #pragma unroll
            for (int e = 0; e < 8; ++e)
                acc[d][e] += vv[d] * kv[e];
        #pragma unroll
        for (int e = 0; e < 8; ++e) acc[8][e] += kv[e];
    }

    __shared__ float red[4][72];
    const int lane = tid & 63, wave = tid >> 6;
    #pragma unroll
    for (int d = 0; d < 9; ++d) {
        #pragma unroll
        for (int e = 0; e < 8; ++e) {
            float v = acc[d][e];
            #pragma unroll
            for (int off = 32; off > 0; off >>= 1) v += __shfl_down(v, off, 64);
            if (lane == 0) red[wave][d * 8 + e] = v;
        }
    }
    __syncthreads();
    if (tid < 72) {
        float v = red[0][tid] + red[1][tid] + red[2][tid] + red[3][tid];
        vk[(size_t)bh * 72 + tid] = v;
    }
}

// ---- attn: head-chunk-transposed write over dead v-rows ----
// chunk(b,h)[n][d] at (base + 16*4096) + n*8 + d  (one 16-B store/thread)
__global__ __launch_bounds__(256) void attn_out_kernel(
    bf16* __restrict__ qkv, bf16* __restrict__ agg,
    const float* __restrict__ vk)
{
    const int b = blockIdx.z;
    const int h = blockIdx.y;
    const int n = blockIdx.x * 256 + threadIdx.x;
    bf16* base = (h < 64)
        ? (qkv + ((size_t)b * 1536 + h * 24) * 4096)
        : (agg + ((size_t)b * 1536 + (h - 64) * 24) * 4096);

    __shared__ float s_vk[72];
    if (threadIdx.x < 72)
        s_vk[threadIdx.x] = vk[((size_t)b * 128 + h) * 72 + threadIdx.x];
    __syncthreads();

    float q[8];
    #pragma unroll
    for (int e = 0; e < 8; ++e) q[e] = fmaxf(b2f(base[(size_t)e * 4096 + n]), 0.f);

    float o[9];
    #pragma unroll
    for (int d = 0; d < 9; ++d) {
        float s = 0.f;
        #pragma unroll
        for (int e = 0; e < 8; ++e) s += s_vk[d * 8 + e] * q[e];
        o[d] = s;
    }
    const float denom = o[8] + 1e-15f;

    union { bf16 hv[8]; uint4 u; } pk;
    #pragma unroll
    for (int d = 0; d < 8; ++d) pk.hv[d] = f2b(o[d] / denom);
    *(uint4*)((char*)(base + (size_t)16 * 4096) + (size_t)n * 16) = pk.u;
}

extern "C" void kernel_launch(void* const* d_in, const int* in_sizes, int n_in,
                              void* d_out, int out_size, void* d_ws, size_t ws_size,
                              hipStream_t stream) {
    const float* x      = (const float*)d_in[0];
    const float* w_qkv  = (const float*)d_in[1];
    const float* w_dw   = (const float*)d_in[2];
    const float* w_pw   = (const float*)d_in[3];
    const float* w_proj = (const float*)d_in[4];

    char* ws = (char*)d_ws;
    bf16* w_qkv_bf  = (bf16*)ws;                               // 1,572,864 B
    bf16* w_proj_bf = (bf16*)(ws + 1572864);                   // 1,048,576 B
    float* vkbf     = (float*)(ws + 1572864 + 1048576);        //   147,456 B
    bf16* x_t       = (bf16*)(ws + 1572864 + 1048576 + 147456);          // 16 MiB
    bf16* qkv       = x_t + (size_t)4 * 4096 * 512;            // 48 MiB
    bf16* agg       = qkv + (size_t)4 * 1536 * 4096;           // 48 MiB

    // 0. weight conversion + x transpose
    convert_kernel<<<3072, 256, 0, stream>>>(w_qkv, w_qkv_bf, 786432);
    convert_kernel<<<2048, 256, 0, stream>>>(w_proj, w_proj_bf, 524288);
    transpose_x_kernel<<<dim3(128, 16, 4), 256, 0, stream>>>(x, x_t);

    // 1. qkv = w_qkv (1536x512) @ x[b]  (MFMA, B^T from x_t)
    mfma_gemm_kernel<false><<<dim3(32, 12, 4), 256, 0, stream>>>(
        w_qkv_bf, x_t, nullptr, nullptr, qkv, 1536, 512);

    // 2. agg = grouped-PW(DW5x5(qkv)) — direct-from-global v4
    dwpw_kernel<<<dim3(4, 768), 128, 0, stream>>>(qkv, w_dw, w_pw, agg);

    // 3. vk per (b, head)
    vk_kernel<<<dim3(512), 256, 0, stream>>>(qkv, agg, vkbf);

    // 4. attn (normalized), head-chunk-transposed over dead v-rows
    attn_out_kernel<<<dim3(16, 128, 4), 256, 0, stream>>>(qkv, agg, vkbf);

    // 5. out = x + w_proj (512x1024) @ attn[b]  (MFMA, B^T from chunks)
    mfma_gemm_kernel<true><<<dim3(32, 4, 4), 256, 0, stream>>>(
        w_proj_bf, qkv, agg, x, d_out, 512, 1024);
}